// Round 11
// baseline (536.389 us; speedup 1.0000x reference)
//
#include <hip/hip_runtime.h>
#include <stdint.h>

#define EPS 1e-3f

typedef _Float16 f16x8 __attribute__((ext_vector_type(8)));
typedef float f32x4 __attribute__((ext_vector_type(4)));
typedef float f32x16 __attribute__((ext_vector_type(16)));

// ---------------------------------------------------------------------------
// Setup: fold BN scale/bias; zero Lc + kstat; pack Wp (proj weights as f16
// MFMA A-frags); prepack w_pos into 32x32x16-MFMA A-frags (u-packed K).
// ---------------------------------------------------------------------------
__global__ __launch_bounds__(256) void setup_kernel(
    const float* __restrict__ w_pos,
    const float* __restrict__ w_q, const float* __restrict__ w_k,
    const float* __restrict__ w_v,
    const float* __restrict__ gq, const float* __restrict__ bq,
    const float* __restrict__ mq, const float* __restrict__ vq,
    const float* __restrict__ gv, const float* __restrict__ bv,
    const float* __restrict__ mv, const float* __restrict__ vvar,
    float* __restrict__ scale_bias, float* __restrict__ Lc,
    float* __restrict__ kstat,
    _Float16* __restrict__ Wp, _Float16* __restrict__ Apack) {
  const int idx = blockIdx.x * 256 + threadIdx.x;
  if (idx < 384) {
    float sc, bi;
    if (idx < 64) {
      const float inv = gq[idx] * rsqrtf(vq[idx] + EPS);
      sc = inv; bi = bq[idx] - mq[idx] * inv;
    } else if (idx < 128) {
      sc = 1.f; bi = 0.f;  // k has no BN
    } else {
      const int o = idx - 128;
      const float inv = gv[o] * rsqrtf(vvar[o] + EPS);
      sc = inv; bi = bv[o] - mv[o] * inv;
    }
    scale_bias[idx] = sc;
    scale_bias[384 + idx] = bi;
  }
  if (idx < 16384) Lc[idx] = 0.f;   // lc_kernel accumulates via atomicAdd
  if (idx < 1024) kstat[idx] = 0.f; // proj_gemm accumulates exp-sums
  if (idx < 98304) {               // Wp A-frag pack: idx = ((mt*16+kt)*64+lane)*8+j
    const int j = idx & 7;
    const int lane = (idx >> 3) & 63;
    const int fr = idx >> 9;       // mt*16 + kt
    const int kt = fr & 15;
    const int mt = fr >> 4;
    const int m = mt * 32 + (lane & 31);
    const int k = kt * 16 + (lane >> 5) * 8 + j;
    float sc; const float* Wsrc;
    if (m < 64) {
      sc = gq[m] * rsqrtf(vq[m] + EPS);
      Wsrc = w_q + (size_t)m * 256;
    } else if (m < 128) {
      sc = 1.f;
      Wsrc = w_k + (size_t)(m - 64) * 256;
    } else {
      const int r = m - 128;
      sc = gv[r] * rsqrtf(vvar[r] + EPS);
      Wsrc = w_v + (size_t)r * 256;
    }
    Wp[idx] = (_Float16)(Wsrc[k] * sc);
  }
  if (idx < 376832) {  // 736 frags * 64 lanes * 8 halfs
    const int j = idx & 7;
    const int lane = (idx >> 3) & 63;
    const int f = idx >> 9;
    const int rel = f & 7;
    const int ss = (f >> 3) % 23;
    const int w = (f >> 3) / 23;
    const int m = lane & 31;
    const int kk = m & 15;
    const int ol = m >> 4;
    const int kap = lane >> 5;
    const int k = kap * 8 + j;
    const int u = k >> 2;
    const int y4 = k & 3;
    const int dy = 4 * rel + y4 - 2 * w - ol;
    float val = 0.f;
    if (dy >= 0 && dy < 23)
      val = w_pos[kk * 2116 + u * 529 + dy * 23 + ss];
    Apack[idx] = (_Float16)val;
  }
}

// ---------------------------------------------------------------------------
// Projection GEMM via f16 MFMA. Block (nchunk=64 of 64 cols, b): A-frag
// reuse x2 (each A feeds MFMAs for col and col+32), halving the L2 A-load
// dependency chain that made the 32-col version latency-bound.
// Epilogue also accumulates k-row exp-sums into kstat (softmax without max
// subtraction: |k| <~ 2, exp f32-safe; shift-invariance makes it exact),
// eliminating the separate kstats kernel.
// ---------------------------------------------------------------------------
__global__ __launch_bounds__(256) void proj_gemm(
    const float* __restrict__ x, const _Float16* __restrict__ Wp,
    const float* __restrict__ scale_bias, float* __restrict__ projq,
    _Float16* __restrict__ projkv, float* __restrict__ kstat) {
  const int b = blockIdx.y;
  const int n0 = blockIdx.x * 64;
  const int tid = threadIdx.x;
  const int w = tid >> 6, lane = tid & 63;
  const int col = lane & 31, kap = lane >> 5;

  __shared__ __align__(16) _Float16 xT[64][264];  // 33792 B

  // stage x f32 -> f16 transposed: xT[n][k]
#pragma unroll
  for (int r = 0; r < 16; ++r) {
    const int i = tid + r * 256;  // 0..4095
    const int k = i >> 4, n4 = (i & 15) * 4;
    const float4 xv = *(const float4*)&x[((size_t)(b * 256 + k)) * 4096 + n0 + n4];
    xT[n4 + 0][k] = (_Float16)xv.x;
    xT[n4 + 1][k] = (_Float16)xv.y;
    xT[n4 + 2][k] = (_Float16)xv.z;
    xT[n4 + 3][k] = (_Float16)xv.w;
  }
  __syncthreads();

  f32x16 acc[3][2];
#pragma unroll
  for (int i = 0; i < 3; ++i) {
    acc[i][0] = (f32x16)0.f;
    acc[i][1] = (f32x16)0.f;
  }

  const f16x8* Wf = (const f16x8*)Wp;
#pragma unroll
  for (int kt = 0; kt < 16; ++kt) {
    const f16x8 B0 =
        *(const f16x8*)__builtin_assume_aligned(&xT[col][kt * 16 + kap * 8], 16);
    const f16x8 B1 =
        *(const f16x8*)__builtin_assume_aligned(&xT[col + 32][kt * 16 + kap * 8], 16);
#pragma unroll
    for (int i = 0; i < 3; ++i) {
      const f16x8 A = Wf[(size_t)(((w * 3 + i) * 16 + kt) * 64) + lane];
      acc[i][0] = __builtin_amdgcn_mfma_f32_32x32x16_f16(A, B0, acc[i][0], 0, 0, 0);
      acc[i][1] = __builtin_amdgcn_mfma_f32_32x32x16_f16(A, B1, acc[i][1], 0, 0, 0);
    }
  }

#pragma unroll
  for (int i = 0; i < 3; ++i) {
    const int mt = w * 3 + i;
#pragma unroll
    for (int reg = 0; reg < 16; ++reg) {
      const int row = (reg & 3) + 8 * (reg >> 2) + 4 * kap;
      const int o = mt * 32 + row;
      const float bi = scale_bias[384 + o];
      const float v0 = acc[i][0][reg] + bi;
      const float v1 = acc[i][1][reg] + bi;
      if (mt < 2) {
        projq[((size_t)(b * 64 + o)) * 4096 + n0 + col] = v0;
        projq[((size_t)(b * 64 + o)) * 4096 + n0 + 32 + col] = v1;
      } else {
        projkv[((size_t)(b * 320 + (o - 64))) * 4096 + n0 + col] = (_Float16)v0;
        projkv[((size_t)(b * 320 + (o - 64))) * 4096 + n0 + 32 + col] = (_Float16)v1;
        if (mt < 4) {  // k rows: accumulate exp-sum (no max subtraction)
          float s = expf(v0) + expf(v1);
#pragma unroll
          for (int off = 16; off > 0; off >>= 1) s += __shfl_xor(s, off);
          if (col == 0) atomicAdd(&kstat[b * 64 + (o - 64)], s);
        }
      }
    }
  }
}

// ---------------------------------------------------------------------------
// Lc: LDS-tiled, atomicAdd partials. f16 k/v inputs; softmax applied at
// k staging: weight = exp(k) / kstat[row]  (no-max scheme, exact by
// shift-invariance).
// ---------------------------------------------------------------------------
__global__ __launch_bounds__(256) void lc_kernel(
    const _Float16* __restrict__ projkv, const float* __restrict__ kstat,
    float* __restrict__ Lc) {
  const int mc = blockIdx.x, b = blockIdx.y;
  const int m0 = mc * 128;
  const int tid = threadIdx.x;
  const int kk = tid & 15;
  const int dvb = tid >> 4;  // 16 groups of 4 dv

  __shared__ float kT[16][132];
  __shared__ float vT[64][132];

  float a0 = 0.f, a1 = 0.f, a2 = 0.f, a3 = 0.f;

  for (int u = 0; u < 4; ++u) {
    __syncthreads();
    {  // k: one f16x8 per thread (16 rows x 128 cols), softmax inline
      const int row = tid >> 4, c8 = (tid & 15) * 8;
      const int ch = u * 16 + row;
      const float kinv = 1.f / kstat[(size_t)b * 64 + ch];
      const f16x8 raw =
          *(const f16x8*)&projkv[((size_t)(b * 320 + ch)) * 4096 + m0 + c8];
#pragma unroll
      for (int e = 0; e < 8; ++e)
        kT[row][c8 + e] = expf((float)raw[e]) * kinv;
    }
#pragma unroll
    for (int r = 0; r < 4; ++r) {  // v: 64 rows x 128 cols f16
      const int i = tid + r * 256;
      const int row = i >> 4, c8 = (i & 15) * 8;
      const f16x8 raw =
          *(const f16x8*)&projkv[((size_t)(b * 320 + 64 + u * 64 + row)) * 4096 + m0 + c8];
#pragma unroll
      for (int e = 0; e < 8; ++e) vT[row][c8 + e] = (float)raw[e];
    }
    __syncthreads();
#pragma unroll 4
    for (int m = 0; m < 128; ++m) {
      const float kv = kT[kk][m];
      a0 = fmaf(kv, vT[dvb * 4 + 0][m], a0);
      a1 = fmaf(kv, vT[dvb * 4 + 1][m], a1);
      a2 = fmaf(kv, vT[dvb * 4 + 2][m], a2);
      a3 = fmaf(kv, vT[dvb * 4 + 3][m], a3);
    }
  }

  float* dst = &Lc[((size_t)(b * 16 + kk)) * 64 + dvb * 4];
  atomicAdd(dst + 0, a0);
  atomicAdd(dst + 1, a1);
  atomicAdd(dst + 2, a2);
  atomicAdd(dst + 3, a3);
}

// ---------------------------------------------------------------------------
// Conv worker: EXACT round-3 configuration (best measured: 330-332 µs).
// Branchless compile-time pruning, s_setprio around MFMA cluster (A/B r7:
// removal cost 20 µs), NO ss-rotation (A/B r3 vs r6: -10 µs), NO XCD swizzle
// (A/B r3 vs r8: -14 µs), 4-deep Bq stream, A-prefetch into dead slots.
// ---------------------------------------------------------------------------
template <int W>
__device__ __forceinline__ void conv_worker(
    const _Float16* __restrict__ vL, const f16x8* __restrict__ Awl,
    const float* __restrict__ qsec, const float* __restrict__ lcb,
    const int n, const int kap, const int b, const int dv,
    float* __restrict__ out) {
  constexpr bool G0 = (W < 2);   // rel0 / tau0 live
  constexpr bool G6 = (W != 0);  // rel6 / tau20 live
  constexpr bool G7 = (W == 3);  // rel7 / tau21 live

  f16x8 A[8];
  if (G0) A[0] = Awl[0 * 64];
#pragma unroll
  for (int r = 1; r < 6; ++r) A[r] = Awl[r * 64];
  if (G6) A[6] = Awl[6 * 64];
  if (G7) A[7] = Awl[7 * 64];

#pragma unroll 1
  for (int pass = 0; pass < 2; ++pass) {
    f32x16 acc[8];
#pragma unroll
    for (int t = 0; t < 8; t++) acc[t] = (f32x16)0.f;

#pragma unroll 1
    for (int ss = 0; ss < 23; ++ss) {
      const int ssn = (ss == 22) ? 0 : ss + 1;  // pass-independent A stream
      const f16x8* Awn = Awl + (size_t)(ssn * 8) * 64;
      const _Float16* brow = &vL[(32 * pass + n + ss) * 360 + 8 * kap];

      f16x8 Bq[22];
      // prologue: taus 0..3
      if (G0) Bq[0] = *(const f16x8*)__builtin_assume_aligned(brow, 16);
#pragma unroll
      for (int tau = 1; tau < 4; ++tau)
        Bq[tau] = *(const f16x8*)__builtin_assume_aligned(brow + 16 * tau, 16);

#pragma unroll
      for (int tau = 0; tau < 22; ++tau) {
        // streaming prefetch, 4 taus ahead (compile-time folded guards)
        const int tpf = tau + 4;
        if (tpf < 22) {
          const bool live = (tpf == 20) ? G6 : (tpf == 21) ? G7 : true;
          if (live)
            Bq[tpf] = *(const f16x8*)__builtin_assume_aligned(brow + 16 * tpf, 16);
        }
        __builtin_amdgcn_s_setprio(1);
#pragma unroll
        for (int t = 0; t < 8; ++t) {
          const int rel = tau - 2 * t;
          if (rel < 0 || rel > 7) continue;
          if ((rel == 0 && !G0) || (rel == 6 && !G6) || (rel == 7 && !G7)) continue;
          acc[t] = __builtin_amdgcn_mfma_f32_32x32x16_f16(A[rel], Bq[tau], acc[t], 0, 0, 0);
        }
        __builtin_amdgcn_s_setprio(0);
        // A prefetch for next ss into dead A[rel] (last use at tau = 14+rel)
        if (tau >= 14) {
          const int rn = tau - 14;
          const bool live = (rn == 0) ? G0 : (rn == 6) ? G6 : (rn == 7) ? G7 : true;
          if (live) A[rn] = Awn[rn * 64];
        }
      }
    }

    // epilogue: for each (t, ol): gamma = 8t + 2W + ol
    const int c = 32 * pass + n;
#pragma unroll 1
    for (int t = 0; t < 8; ++t) {
#pragma unroll
      for (int ol = 0; ol < 2; ++ol) {
        const int gamma = 8 * t + 2 * W + ol;
        const float* qg = qsec + (size_t)gamma * 64 + c;
        float y0 = 0.f, y1 = 0.f, y2 = 0.f, y3 = 0.f;
#pragma unroll
        for (int e = 0; e < 8; ++e) {
          const int kk = (e & 3) + 8 * (e >> 2) + 4 * kap;
          const float cf = acc[t][ol * 8 + e] + lcb[e];
          y0 = fmaf(qg[(size_t)(kk) * 4096], cf, y0);
          y1 = fmaf(qg[(size_t)(16 + kk) * 4096], cf, y1);
          y2 = fmaf(qg[(size_t)(32 + kk) * 4096], cf, y2);
          y3 = fmaf(qg[(size_t)(48 + kk) * 4096], cf, y3);
        }
        y0 += __shfl_xor(y0, 32);
        y1 += __shfl_xor(y1, 32);
        y2 += __shfl_xor(y2, 32);
        y3 += __shfl_xor(y3, 32);
        const float s0 = kap ? y2 : y0;  // h = 2*kap
        const float s1 = kap ? y3 : y1;  // h = 2*kap + 1
        out[((size_t)(b * 256 + (2 * kap + 0) * 64 + dv)) * 4096 + gamma * 64 + c] = s0;
        out[((size_t)(b * 256 + (2 * kap + 1) * 64 + dv)) * 4096 + gamma * 64 + c] = s1;
      }
    }
  }
}

// ---------------------------------------------------------------------------
// MFMA position-conv + Yp + Yc. Block = (dv, b) plain mapping (r3 config).
// v staged from f16 projkv (pure repack, no convert).
// ---------------------------------------------------------------------------
__global__ __launch_bounds__(256, 2) void lambda_conv(
    const float* __restrict__ projq, const _Float16* __restrict__ projkv,
    const _Float16* __restrict__ Apack,
    const float* __restrict__ Lc, const float* __restrict__ b_pos,
    float* __restrict__ out) {
  const int dv = blockIdx.x;
  const int b = blockIdx.y;
  const int tid = threadIdx.x;
  const int w = tid >> 6;          // wave: off pair base {2w, 2w+1}
  const int lane = tid & 63;
  const int n = lane & 31;         // output col within pass
  const int kap = lane >> 5;

  __shared__ __align__(16) _Float16 vL[86 * 360];  // 61920 B

  // zero LDS (x- and y-halo)
  {
    const uint4 z = {0u, 0u, 0u, 0u};
    for (int i = tid; i < (86 * 360 * 2) / 16; i += 256) ((uint4*)vL)[i] = z;
  }
  __syncthreads();

  // stage v (f16 -> f16 repack), transposed + u-packed: vL[x+11][sy>>2][u][sy&3]
  {
    const _Float16* vsec = projkv + ((size_t)(b * 320 + 64 + dv)) * 4096;
    for (int idx = tid; idx < 2048; idx += 256) {
      const int u = idx >> 9, g = (idx >> 3) & 63, c8 = (idx & 7) * 8;
      const f16x8 vv = *(const f16x8*)&vsec[(size_t)u * 262144 + g * 64 + c8];
      const int sy = g + 11;
      const int qoff = (sy >> 2) * 16 + (u << 2) + (sy & 3);
      _Float16* base = &vL[(c8 + 11) * 360 + qoff];
#pragma unroll
      for (int e = 0; e < 8; ++e) base[(size_t)e * 360] = vv[e];
    }
  }
  __syncthreads();

  // Lc + b_pos for this lane's 8 kk channels: kk_e = (e&3) + 8*(e>>2) + 4*kap
  float lcb[8];
#pragma unroll
  for (int e = 0; e < 8; e++) {
    const int kk = (e & 3) + 8 * (e >> 2) + 4 * kap;
    lcb[e] = Lc[(b * 16 + kk) * 64 + dv] + b_pos[kk];
  }

  const float* qsec = projq + ((size_t)(b * 64)) * 4096;
  const f16x8* Ap = (const f16x8*)Apack;
  const f16x8* Awl = Ap + (size_t)(w * 184) * 64 + lane;  // frag (ss*8+rel)*64

  switch (w) {
    case 0: conv_worker<0>(vL, Awl, qsec, lcb, n, kap, b, dv, out); break;
    case 1: conv_worker<1>(vL, Awl, qsec, lcb, n, kap, b, dv, out); break;
    case 2: conv_worker<2>(vL, Awl, qsec, lcb, n, kap, b, dv, out); break;
    default: conv_worker<3>(vL, Awl, qsec, lcb, n, kap, b, dv, out); break;
  }
}

// ---------------------------------------------------------------------------
extern "C" void kernel_launch(void* const* d_in, const int* in_sizes, int n_in,
                              void* d_out, int out_size, void* d_ws, size_t ws_size,
                              hipStream_t stream) {
  const float* x       = (const float*)d_in[0];
  const float* w_q     = (const float*)d_in[1];
  const float* w_k     = (const float*)d_in[2];
  const float* w_v     = (const float*)d_in[3];
  const float* gamma_q = (const float*)d_in[4];
  const float* beta_q  = (const float*)d_in[5];
  const float* mean_q  = (const float*)d_in[6];
  const float* var_q   = (const float*)d_in[7];
  const float* gamma_v = (const float*)d_in[8];
  const float* beta_v  = (const float*)d_in[9];
  const float* mean_v  = (const float*)d_in[10];
  const float* var_v   = (const float*)d_in[11];
  const float* w_pos   = (const float*)d_in[12];
  const float* b_pos   = (const float*)d_in[13];

  float* ws = (float*)d_ws;
  float* projq = ws;                                   // 4194304 floats
  _Float16* projkv = (_Float16*)(ws + 4194304);        // 20971520 halfs
  float* sb = ws + 4194304 + 10485760;                 // 768 floats
  float* Lc = sb + 768;                                // 16384 floats
  _Float16* Apack = (_Float16*)(Lc + 16384);           // 376832 halfs
  _Float16* Wp = Apack + 376832;                       // 98304 halfs
  float* kstat = (float*)(Wp + 98304);                 // 1024 floats
  float* out = (float*)d_out;

  setup_kernel<<<1472, 256, 0, stream>>>(w_pos, w_q, w_k, w_v,
                                         gamma_q, beta_q, mean_q, var_q,
                                         gamma_v, beta_v, mean_v, var_v,
                                         sb, Lc, kstat, Wp, Apack);
  proj_gemm<<<dim3(64, 16), 256, 0, stream>>>(x, Wp, sb, projq, projkv, kstat);
  lc_kernel<<<dim3(32, 16), 256, 0, stream>>>(projkv, kstat, Lc);
  lambda_conv<<<dim3(64, 16), 256, 0, stream>>>(projq, projkv, Apack, Lc, b_pos, out);
}

// Round 12
// 514.015 us; speedup vs baseline: 1.0435x; 1.0435x over previous
//
#include <hip/hip_runtime.h>
#include <stdint.h>

#define EPS 1e-3f

typedef _Float16 f16x8 __attribute__((ext_vector_type(8)));
typedef float f32x4 __attribute__((ext_vector_type(4)));
typedef float f32x16 __attribute__((ext_vector_type(16)));

// ---------------------------------------------------------------------------
// Setup: fold BN scale/bias; zero Lc; pack Wp (proj weights as f16 MFMA
// A-frags); prepack w_pos into 32x32x16-MFMA A-frags (u-packed K).
// ---------------------------------------------------------------------------
__global__ __launch_bounds__(256) void setup_kernel(
    const float* __restrict__ w_pos,
    const float* __restrict__ w_q, const float* __restrict__ w_k,
    const float* __restrict__ w_v,
    const float* __restrict__ gq, const float* __restrict__ bq,
    const float* __restrict__ mq, const float* __restrict__ vq,
    const float* __restrict__ gv, const float* __restrict__ bv,
    const float* __restrict__ mv, const float* __restrict__ vvar,
    float* __restrict__ scale_bias, float* __restrict__ Lc,
    _Float16* __restrict__ Wp, _Float16* __restrict__ Apack) {
  const int idx = blockIdx.x * 256 + threadIdx.x;
  if (idx < 384) {
    float sc, bi;
    if (idx < 64) {
      const float inv = gq[idx] * rsqrtf(vq[idx] + EPS);
      sc = inv; bi = bq[idx] - mq[idx] * inv;
    } else if (idx < 128) {
      sc = 1.f; bi = 0.f;  // k has no BN
    } else {
      const int o = idx - 128;
      const float inv = gv[o] * rsqrtf(vvar[o] + EPS);
      sc = inv; bi = bv[o] - mv[o] * inv;
    }
    scale_bias[idx] = sc;
    scale_bias[384 + idx] = bi;
  }
  if (idx < 16384) Lc[idx] = 0.f;  // lc_kernel accumulates via atomicAdd
  if (idx < 98304) {               // Wp A-frag pack: idx = ((mt*16+kt)*64+lane)*8+j
    const int j = idx & 7;
    const int lane = (idx >> 3) & 63;
    const int fr = idx >> 9;       // mt*16 + kt
    const int kt = fr & 15;
    const int mt = fr >> 4;
    const int m = mt * 32 + (lane & 31);
    const int k = kt * 16 + (lane >> 5) * 8 + j;
    float sc; const float* Wsrc;
    if (m < 64) {
      sc = gq[m] * rsqrtf(vq[m] + EPS);
      Wsrc = w_q + (size_t)m * 256;
    } else if (m < 128) {
      sc = 1.f;
      Wsrc = w_k + (size_t)(m - 64) * 256;
    } else {
      const int r = m - 128;
      sc = gv[r] * rsqrtf(vvar[r] + EPS);
      Wsrc = w_v + (size_t)r * 256;
    }
    Wp[idx] = (_Float16)(Wsrc[k] * sc);
  }
  if (idx < 376832) {  // 736 frags * 64 lanes * 8 halfs
    const int j = idx & 7;
    const int lane = (idx >> 3) & 63;
    const int f = idx >> 9;
    const int rel = f & 7;
    const int ss = (f >> 3) % 23;
    const int w = (f >> 3) / 23;
    const int m = lane & 31;
    const int kk = m & 15;
    const int ol = m >> 4;
    const int kap = lane >> 5;
    const int k = kap * 8 + j;
    const int u = k >> 2;
    const int y4 = k & 3;
    const int dy = 4 * rel + y4 - 2 * w - ol;
    float val = 0.f;
    if (dy >= 0 && dy < 23)
      val = w_pos[kk * 2116 + u * 529 + dy * 23 + ss];
    Apack[idx] = (_Float16)val;
  }
}

// ---------------------------------------------------------------------------
// Projection GEMM via f16 MFMA. Block (nchunk=128 of 32 cols, b).
// Output split: q rows (o<64) -> projq f32 (epilogue consumes f32);
// k+v rows -> projkv f16 (all consumers convert to/accept f16 anyway).
// (A/B r11: 64-col A-frag-reuse variant with fused kstat regressed +30 µs;
// this 32-col + separate-kstats config is the measured best.)
// ---------------------------------------------------------------------------
__global__ __launch_bounds__(256) void proj_gemm(
    const float* __restrict__ x, const _Float16* __restrict__ Wp,
    const float* __restrict__ scale_bias, float* __restrict__ projq,
    _Float16* __restrict__ projkv) {
  const int b = blockIdx.y;
  const int n0 = blockIdx.x * 32;
  const int tid = threadIdx.x;
  const int w = tid >> 6, lane = tid & 63;
  const int col = lane & 31, kap = lane >> 5;

  __shared__ __align__(16) _Float16 xT[32][264];  // 16896 B

  // stage x f32 -> f16 transposed: xT[n][k]
#pragma unroll
  for (int r = 0; r < 8; ++r) {
    const int i = tid + r * 256;  // 0..2047
    const int k = i >> 3, n4 = (i & 7) * 4;
    const float4 xv = *(const float4*)&x[((size_t)(b * 256 + k)) * 4096 + n0 + n4];
    xT[n4 + 0][k] = (_Float16)xv.x;
    xT[n4 + 1][k] = (_Float16)xv.y;
    xT[n4 + 2][k] = (_Float16)xv.z;
    xT[n4 + 3][k] = (_Float16)xv.w;
  }
  __syncthreads();

  f32x16 acc[3];
#pragma unroll
  for (int i = 0; i < 3; ++i) acc[i] = (f32x16)0.f;

  const f16x8* Wf = (const f16x8*)Wp;
#pragma unroll
  for (int kt = 0; kt < 16; ++kt) {
    const f16x8 B =
        *(const f16x8*)__builtin_assume_aligned(&xT[col][kt * 16 + kap * 8], 16);
#pragma unroll
    for (int i = 0; i < 3; ++i) {
      const f16x8 A = Wf[(size_t)(((w * 3 + i) * 16 + kt) * 64) + lane];
      acc[i] = __builtin_amdgcn_mfma_f32_32x32x16_f16(A, B, acc[i], 0, 0, 0);
    }
  }

#pragma unroll
  for (int i = 0; i < 3; ++i) {
    const int mt = w * 3 + i;
#pragma unroll
    for (int reg = 0; reg < 16; ++reg) {
      const int row = (reg & 3) + 8 * (reg >> 2) + 4 * kap;
      const int o = mt * 32 + row;
      const float val = acc[i][reg] + scale_bias[384 + o];
      if (mt < 2)
        projq[((size_t)(b * 64 + o)) * 4096 + n0 + col] = val;
      else
        projkv[((size_t)(b * 320 + (o - 64))) * 4096 + n0 + col] = (_Float16)val;
    }
  }
}

// ---------------------------------------------------------------------------
// k softmax STATS only (max, 1/sum per row) from f16 k.
// ---------------------------------------------------------------------------
__global__ __launch_bounds__(256) void kstats_kernel(
    const _Float16* __restrict__ projkv, float* __restrict__ kstat) {
  const int row = blockIdx.x;          // 0..1023 = b*64 + ch
  const int b = row >> 6, c = row & 63;
  const f16x8* p8 = (const f16x8*)(projkv + ((size_t)(b * 320 + c)) * 4096);
  const int tid = threadIdx.x;

  f16x8 h[2];
  h[0] = p8[tid];
  h[1] = p8[tid + 256];
  float vmax = -3.4e38f;
#pragma unroll
  for (int i = 0; i < 2; ++i)
#pragma unroll
    for (int e = 0; e < 8; ++e) vmax = fmaxf(vmax, (float)h[i][e]);
#pragma unroll
  for (int off = 32; off > 0; off >>= 1) vmax = fmaxf(vmax, __shfl_xor(vmax, off));
  __shared__ float redm[4], reds[4];
  if ((tid & 63) == 0) redm[tid >> 6] = vmax;
  __syncthreads();
  vmax = fmaxf(fmaxf(redm[0], redm[1]), fmaxf(redm[2], redm[3]));

  float sum = 0.f;
#pragma unroll
  for (int i = 0; i < 2; ++i)
#pragma unroll
    for (int e = 0; e < 8; ++e) sum += expf((float)h[i][e] - vmax);
#pragma unroll
  for (int off = 32; off > 0; off >>= 1) sum += __shfl_xor(sum, off);
  if ((tid & 63) == 0) reds[tid >> 6] = sum;
  __syncthreads();
  sum = reds[0] + reds[1] + reds[2] + reds[3];
  if (tid == 0) {
    kstat[(size_t)row * 2 + 0] = vmax;
    kstat[(size_t)row * 2 + 1] = 1.f / sum;
  }
}

// ---------------------------------------------------------------------------
// Lc: LDS-tiled, atomicAdd partials. f16 k/v inputs; softmax applied at
// k staging using kstat.
// ---------------------------------------------------------------------------
__global__ __launch_bounds__(256) void lc_kernel(
    const _Float16* __restrict__ projkv, const float* __restrict__ kstat,
    float* __restrict__ Lc) {
  const int mc = blockIdx.x, b = blockIdx.y;
  const int m0 = mc * 128;
  const int tid = threadIdx.x;
  const int kk = tid & 15;
  const int dvb = tid >> 4;  // 16 groups of 4 dv

  __shared__ float kT[16][132];
  __shared__ float vT[64][132];

  float a0 = 0.f, a1 = 0.f, a2 = 0.f, a3 = 0.f;

  for (int u = 0; u < 4; ++u) {
    __syncthreads();
    {  // k: one f16x8 per thread (16 rows x 128 cols), softmax inline
      const int row = tid >> 4, c8 = (tid & 15) * 8;
      const int ch = u * 16 + row;
      const float kmax = kstat[((size_t)b * 64 + ch) * 2 + 0];
      const float kinv = kstat[((size_t)b * 64 + ch) * 2 + 1];
      const f16x8 raw =
          *(const f16x8*)&projkv[((size_t)(b * 320 + ch)) * 4096 + m0 + c8];
#pragma unroll
      for (int e = 0; e < 8; ++e)
        kT[row][c8 + e] = expf((float)raw[e] - kmax) * kinv;
    }
#pragma unroll
    for (int r = 0; r < 4; ++r) {  // v: 64 rows x 128 cols f16
      const int i = tid + r * 256;
      const int row = i >> 4, c8 = (i & 15) * 8;
      const f16x8 raw =
          *(const f16x8*)&projkv[((size_t)(b * 320 + 64 + u * 64 + row)) * 4096 + m0 + c8];
#pragma unroll
      for (int e = 0; e < 8; ++e) vT[row][c8 + e] = (float)raw[e];
    }
    __syncthreads();
#pragma unroll 4
    for (int m = 0; m < 128; ++m) {
      const float kv = kT[kk][m];
      a0 = fmaf(kv, vT[dvb * 4 + 0][m], a0);
      a1 = fmaf(kv, vT[dvb * 4 + 1][m], a1);
      a2 = fmaf(kv, vT[dvb * 4 + 2][m], a2);
      a3 = fmaf(kv, vT[dvb * 4 + 3][m], a3);
    }
  }

  float* dst = &Lc[((size_t)(b * 16 + kk)) * 64 + dvb * 4];
  atomicAdd(dst + 0, a0);
  atomicAdd(dst + 1, a1);
  atomicAdd(dst + 2, a2);
  atomicAdd(dst + 3, a3);
}

// ---------------------------------------------------------------------------
// Conv worker: EXACT round-3 configuration (best measured: ~330 µs).
// Branchless compile-time pruning, s_setprio around MFMA cluster (A/B r7:
// removal cost 20 µs), NO ss-rotation (A/B r3 vs r6: -10 µs), NO XCD swizzle
// (A/B r3 vs r8: -14 µs), 4-deep Bq stream, A-prefetch into dead slots.
// ---------------------------------------------------------------------------
template <int W>
__device__ __forceinline__ void conv_worker(
    const _Float16* __restrict__ vL, const f16x8* __restrict__ Awl,
    const float* __restrict__ qsec, const float* __restrict__ lcb,
    const int n, const int kap, const int b, const int dv,
    float* __restrict__ out) {
  constexpr bool G0 = (W < 2);   // rel0 / tau0 live
  constexpr bool G6 = (W != 0);  // rel6 / tau20 live
  constexpr bool G7 = (W == 3);  // rel7 / tau21 live

  f16x8 A[8];
  if (G0) A[0] = Awl[0 * 64];
#pragma unroll
  for (int r = 1; r < 6; ++r) A[r] = Awl[r * 64];
  if (G6) A[6] = Awl[6 * 64];
  if (G7) A[7] = Awl[7 * 64];

#pragma unroll 1
  for (int pass = 0; pass < 2; ++pass) {
    f32x16 acc[8];
#pragma unroll
    for (int t = 0; t < 8; t++) acc[t] = (f32x16)0.f;

#pragma unroll 1
    for (int ss = 0; ss < 23; ++ss) {
      const int ssn = (ss == 22) ? 0 : ss + 1;  // pass-independent A stream
      const f16x8* Awn = Awl + (size_t)(ssn * 8) * 64;
      const _Float16* brow = &vL[(32 * pass + n + ss) * 360 + 8 * kap];

      f16x8 Bq[22];
      // prologue: taus 0..3
      if (G0) Bq[0] = *(const f16x8*)__builtin_assume_aligned(brow, 16);
#pragma unroll
      for (int tau = 1; tau < 4; ++tau)
        Bq[tau] = *(const f16x8*)__builtin_assume_aligned(brow + 16 * tau, 16);

#pragma unroll
      for (int tau = 0; tau < 22; ++tau) {
        // streaming prefetch, 4 taus ahead (compile-time folded guards)
        const int tpf = tau + 4;
        if (tpf < 22) {
          const bool live = (tpf == 20) ? G6 : (tpf == 21) ? G7 : true;
          if (live)
            Bq[tpf] = *(const f16x8*)__builtin_assume_aligned(brow + 16 * tpf, 16);
        }
        __builtin_amdgcn_s_setprio(1);
#pragma unroll
        for (int t = 0; t < 8; ++t) {
          const int rel = tau - 2 * t;
          if (rel < 0 || rel > 7) continue;
          if ((rel == 0 && !G0) || (rel == 6 && !G6) || (rel == 7 && !G7)) continue;
          acc[t] = __builtin_amdgcn_mfma_f32_32x32x16_f16(A[rel], Bq[tau], acc[t], 0, 0, 0);
        }
        __builtin_amdgcn_s_setprio(0);
        // A prefetch for next ss into dead A[rel] (last use at tau = 14+rel)
        if (tau >= 14) {
          const int rn = tau - 14;
          const bool live = (rn == 0) ? G0 : (rn == 6) ? G6 : (rn == 7) ? G7 : true;
          if (live) A[rn] = Awn[rn * 64];
        }
      }
    }

    // epilogue: for each (t, ol): gamma = 8t + 2W + ol
    const int c = 32 * pass + n;
#pragma unroll 1
    for (int t = 0; t < 8; ++t) {
#pragma unroll
      for (int ol = 0; ol < 2; ++ol) {
        const int gamma = 8 * t + 2 * W + ol;
        const float* qg = qsec + (size_t)gamma * 64 + c;
        float y0 = 0.f, y1 = 0.f, y2 = 0.f, y3 = 0.f;
#pragma unroll
        for (int e = 0; e < 8; ++e) {
          const int kk = (e & 3) + 8 * (e >> 2) + 4 * kap;
          const float cf = acc[t][ol * 8 + e] + lcb[e];
          y0 = fmaf(qg[(size_t)(kk) * 4096], cf, y0);
          y1 = fmaf(qg[(size_t)(16 + kk) * 4096], cf, y1);
          y2 = fmaf(qg[(size_t)(32 + kk) * 4096], cf, y2);
          y3 = fmaf(qg[(size_t)(48 + kk) * 4096], cf, y3);
        }
        y0 += __shfl_xor(y0, 32);
        y1 += __shfl_xor(y1, 32);
        y2 += __shfl_xor(y2, 32);
        y3 += __shfl_xor(y3, 32);
        const float s0 = kap ? y2 : y0;  // h = 2*kap
        const float s1 = kap ? y3 : y1;  // h = 2*kap + 1
        out[((size_t)(b * 256 + (2 * kap + 0) * 64 + dv)) * 4096 + gamma * 64 + c] = s0;
        out[((size_t)(b * 256 + (2 * kap + 1) * 64 + dv)) * 4096 + gamma * 64 + c] = s1;
      }
    }
  }
}

// ---------------------------------------------------------------------------
// MFMA position-conv + Yp + Yc. Block = (dv, b) plain mapping (r3 config).
// v staged from f16 projkv (pure repack, no convert).
// ---------------------------------------------------------------------------
__global__ __launch_bounds__(256, 2) void lambda_conv(
    const float* __restrict__ projq, const _Float16* __restrict__ projkv,
    const _Float16* __restrict__ Apack,
    const float* __restrict__ Lc, const float* __restrict__ b_pos,
    float* __restrict__ out) {
  const int dv = blockIdx.x;
  const int b = blockIdx.y;
  const int tid = threadIdx.x;
  const int w = tid >> 6;          // wave: off pair base {2w, 2w+1}
  const int lane = tid & 63;
  const int n = lane & 31;         // output col within pass
  const int kap = lane >> 5;

  __shared__ __align__(16) _Float16 vL[86 * 360];  // 61920 B

  // zero LDS (x- and y-halo)
  {
    const uint4 z = {0u, 0u, 0u, 0u};
    for (int i = tid; i < (86 * 360 * 2) / 16; i += 256) ((uint4*)vL)[i] = z;
  }
  __syncthreads();

  // stage v (f16 -> f16 repack), transposed + u-packed: vL[x+11][sy>>2][u][sy&3]
  {
    const _Float16* vsec = projkv + ((size_t)(b * 320 + 64 + dv)) * 4096;
    for (int idx = tid; idx < 2048; idx += 256) {
      const int u = idx >> 9, g = (idx >> 3) & 63, c8 = (idx & 7) * 8;
      const f16x8 vv = *(const f16x8*)&vsec[(size_t)u * 262144 + g * 64 + c8];
      const int sy = g + 11;
      const int qoff = (sy >> 2) * 16 + (u << 2) + (sy & 3);
      _Float16* base = &vL[(c8 + 11) * 360 + qoff];
#pragma unroll
      for (int e = 0; e < 8; ++e) base[(size_t)e * 360] = vv[e];
    }
  }
  __syncthreads();

  // Lc + b_pos for this lane's 8 kk channels: kk_e = (e&3) + 8*(e>>2) + 4*kap
  float lcb[8];
#pragma unroll
  for (int e = 0; e < 8; e++) {
    const int kk = (e & 3) + 8 * (e >> 2) + 4 * kap;
    lcb[e] = Lc[(b * 16 + kk) * 64 + dv] + b_pos[kk];
  }

  const float* qsec = projq + ((size_t)(b * 64)) * 4096;
  const f16x8* Ap = (const f16x8*)Apack;
  const f16x8* Awl = Ap + (size_t)(w * 184) * 64 + lane;  // frag (ss*8+rel)*64

  switch (w) {
    case 0: conv_worker<0>(vL, Awl, qsec, lcb, n, kap, b, dv, out); break;
    case 1: conv_worker<1>(vL, Awl, qsec, lcb, n, kap, b, dv, out); break;
    case 2: conv_worker<2>(vL, Awl, qsec, lcb, n, kap, b, dv, out); break;
    default: conv_worker<3>(vL, Awl, qsec, lcb, n, kap, b, dv, out); break;
  }
}

// ---------------------------------------------------------------------------
extern "C" void kernel_launch(void* const* d_in, const int* in_sizes, int n_in,
                              void* d_out, int out_size, void* d_ws, size_t ws_size,
                              hipStream_t stream) {
  const float* x       = (const float*)d_in[0];
  const float* w_q     = (const float*)d_in[1];
  const float* w_k     = (const float*)d_in[2];
  const float* w_v     = (const float*)d_in[3];
  const float* gamma_q = (const float*)d_in[4];
  const float* beta_q  = (const float*)d_in[5];
  const float* mean_q  = (const float*)d_in[6];
  const float* var_q   = (const float*)d_in[7];
  const float* gamma_v = (const float*)d_in[8];
  const float* beta_v  = (const float*)d_in[9];
  const float* mean_v  = (const float*)d_in[10];
  const float* var_v   = (const float*)d_in[11];
  const float* w_pos   = (const float*)d_in[12];
  const float* b_pos   = (const float*)d_in[13];

  float* ws = (float*)d_ws;
  float* projq = ws;                                   // 4194304 floats
  _Float16* projkv = (_Float16*)(ws + 4194304);        // 20971520 halfs
  float* sb = ws + 4194304 + 10485760;                 // 768 floats
  float* Lc = sb + 768;                                // 16384 floats
  _Float16* Apack = (_Float16*)(Lc + 16384);           // 376832 halfs
  _Float16* Wp = Apack + 376832;                       // 98304 halfs
  float* kstat = (float*)(Wp + 98304);                 // 2048 floats
  float* out = (float*)d_out;

  setup_kernel<<<1472, 256, 0, stream>>>(w_pos, w_q, w_k, w_v,
                                         gamma_q, beta_q, mean_q, var_q,
                                         gamma_v, beta_v, mean_v, var_v,
                                         sb, Lc, Wp, Apack);
  proj_gemm<<<dim3(128, 16), 256, 0, stream>>>(x, Wp, sb, projq, projkv);
  kstats_kernel<<<1024, 256, 0, stream>>>(projkv, kstat);
  lc_kernel<<<dim3(32, 16), 256, 0, stream>>>(projkv, kstat, Lc);
  lambda_conv<<<dim3(64, 16), 256, 0, stream>>>(projq, projkv, Apack, Lc, b_pos, out);
}